// Round 12
// baseline (19.082 us; speedup 1.0000x reference)
//
#include <hip/hip_runtime.h>

// DMLoss: B=1024, Np=Ng=128, T=10.
// Round 12: r11 structure + __launch_bounds__(512, 8).
//  HYPOTHESIS: r11's regression (19.0 vs r10's 17.25) was a VGPR-driven
//  occupancy drop: 512-thr blocks need VGPR<=64 for 4 blocks/CU (8 waves/EU);
//  r11's extra live state (2 queries + 2 vertices + 8 trackers) let the
//  unconstrained allocator exceed it -> 3 blocks/CU -> +1/3 block-latency.
//  The launch-bounds pin caps VGPR at 64 (hand count of hot-loop state ~35,
//  so no spill expected) and should realize r11's modeled ~3us LDS saving.
//  Everything else identical to r11:
//  - lane = grp(0..7)*8 + sub(0..7); 2 points/thread; part1 16 iters x
//    (b128+b32); part2 8 iters x b128 serving 4 evals.
//  - pads: s_seg/s_g stride-17, s_ini2 stride-9 (disjoint group banks).
//  - combine: (d,idx) packed u32, 3 umin+shfl_xor steps, truncated-tie ->
//    lower index (jnp.argmin first-occurrence).
//  - LESSONS kept: tables not recomputed in-loop (r6/r9); no cross-block
//    atomics (r3/r7); rcp once in staging; exact t/10.0f in epilogue.

constexpr int NP = 128;
constexpr int NG = 128;

__device__ __forceinline__ int pad17(int i) { return i + (i >> 4); }
__device__ __forceinline__ int pad9 (int i) { return i + (i >> 3); }

__global__ __launch_bounds__(512, 8) void dm_main(
    const float* __restrict__ ini,   // [B, NP, 2]
    const float* __restrict__ pp,    // [B, NP, 2]
    const float* __restrict__ gt,    // [B, NG, 2]
    const float* __restrict__ mask,  // [B, NG]
    float* __restrict__ partial,     // SoA: [3][B]
    int nb)
{
    const int b    = blockIdx.x;
    const int tid  = threadIdx.x;
    const int lane = tid & 63;
    const int w    = tid >> 6;             // wave 0..7

    __shared__ float2 s_gt  [NG];          // epilogue gathers (unpadded)
    __shared__ float4 s_seg [NG + 8];      // pad17: {pv.x, pv.y, e10x, e10y}
    __shared__ float  s_g   [NG + 8];      // pad17: |e|^2/100
    __shared__ float4 s_ini2[64 + 8];      // pad9:  {p0.x,p0.y,p1.x,p1.y}
    __shared__ float2 s_pp  [NP];          // epilogue gathers (unpadded)
    __shared__ float  s_red [24];

    const float2* gtb  = (const float2*)(gt  + (size_t)b * 256);
    const float4* ini4 = (const float4*)(ini + (size_t)b * 256);
    const float2* ppb  = (const float2*)(pp  + (size_t)b * 256);

    // Staging; rcp once per segment here (r6/r9 lesson: never in-loop).
    if (tid < 128) {
        const float2 cv = gtb[tid];
        const float2 pv = gtb[(tid + 127) & 127];
        const float ex = cv.x - pv.x, ey = cv.y - pv.y;
        const float ee = fmaf(ex, ex, ey * ey);
        const float s10 = 10.0f * __builtin_amdgcn_rcpf(fmaxf(ee, 1e-30f));
        s_gt [tid]        = cv;
        s_seg[pad17(tid)] = make_float4(pv.x, pv.y, ex * s10, ey * s10);
        s_g  [pad17(tid)] = ee * 0.01f;
    } else if (tid < 192) {
        const int i = tid - 128;
        s_ini2[pad9(i)] = ini4[i];
    } else if (tid < 320) {
        s_pp[tid - 192] = ppb[tid - 192];
    }

    const int sub  = lane & 7;             // point/vertex sub-index
    const int grp  = lane >> 3;            // 0..7 segment/pred group
    const int pnt0 = (w << 4) | sub;       // w*16+sub
    const int pnt1 = pnt0 + 8;
    float mv0 = 0.0f, mv1 = 0.0f;
    if (grp == 0) {
        mv0 = mask[(size_t)b * NG + pnt0];
        mv1 = mask[(size_t)b * NG + pnt1];
    }
    __syncthreads();

    // Queries (one-time reads from packed pair table)
    const float4 qa = s_ini2[pad9((w << 3) + (sub >> 1))];
    const float4 qb = s_ini2[pad9((w << 3) + 4 + (sub >> 1))];
    const float2 q0 = (sub & 1) ? make_float2(qa.z, qa.w) : make_float2(qa.x, qa.y);
    const float2 q1 = (sub & 1) ? make_float2(qb.z, qb.w) : make_float2(qb.x, qb.y);
    const float2 gv0 = s_gt[pnt0];
    const float2 gv1 = s_gt[pnt1];

    // ---- Part 1 scan: segments [grp*16, +16) for points pnt0, pnt1 ----
    float bd10 = 3.4e38f, bi10 = 0.0f, bd11 = 3.4e38f, bi11 = 0.0f;
    {
        const int s0 = grp << 4;
        float basef = (float)(s0 * 10);
        #pragma unroll
        for (int k = 0; k < 16; ++k) {
            const float4 sg = s_seg[pad17(s0 + k)];  // b128, disjoint group banks
            const float  g  = s_g  [pad17(s0 + k)];  // b32, distinct group banks
            {
                const float wx = q0.x - sg.x, wy = q0.y - sg.y;
                const float tf = fmaf(wy, sg.w, wx * sg.z);
                float tc = rintf(tf);
                tc = __builtin_amdgcn_fmed3f(tc, 0.0f, 9.0f);
                const float ww = fmaf(wy, wy, wx * wx);
                const float d  = fmaf(g * tc, fmaf(-2.0f, tf, tc), ww);
                const float cand = basef + tc;
                bi10 = (d < bd10) ? cand : bi10;     // strict <: first occurrence
                bd10 = fminf(d, bd10);
            }
            {
                const float wx = q1.x - sg.x, wy = q1.y - sg.y;
                const float tf = fmaf(wy, sg.w, wx * sg.z);
                float tc = rintf(tf);
                tc = __builtin_amdgcn_fmed3f(tc, 0.0f, 9.0f);
                const float ww = fmaf(wy, wy, wx * wx);
                const float d  = fmaf(g * tc, fmaf(-2.0f, tf, tc), ww);
                const float cand = basef + tc;
                bi11 = (d < bd11) ? cand : bi11;
                bd11 = fminf(d, bd11);
            }
            basef += 10.0f;
        }
    }

    // ---- Part 2 scan: pred pairs [grp*8, +8) for vertices pnt0, pnt1 ----
    float bd20 = 3.4e38f, bj20 = 0.0f, bd21 = 3.4e38f, bj21 = 0.0f;
    {
        const int p0 = grp << 3;
        float jf = (float)(grp << 4);
        #pragma unroll
        for (int k = 0; k < 8; ++k) {
            const float4 pv2 = s_ini2[pad9(p0 + k)]; // one b128 -> 4 evals
            {
                const float dx = gv0.x - pv2.x, dy = gv0.y - pv2.y;
                const float d  = fmaf(dy, dy, dx * dx);
                bj20 = (d < bd20) ? jf : bj20;
                bd20 = fminf(d, bd20);
            }
            {
                const float dx = gv1.x - pv2.x, dy = gv1.y - pv2.y;
                const float d  = fmaf(dy, dy, dx * dx);
                bj21 = (d < bd21) ? jf : bj21;
                bd21 = fminf(d, bd21);
            }
            jf += 1.0f;
            {
                const float dx = gv0.x - pv2.z, dy = gv0.y - pv2.w;
                const float d  = fmaf(dy, dy, dx * dx);
                bj20 = (d < bd20) ? jf : bj20;
                bd20 = fminf(d, bd20);
            }
            {
                const float dx = gv1.x - pv2.z, dy = gv1.y - pv2.w;
                const float d  = fmaf(dy, dy, dx * dx);
                bj21 = (d < bd21) ? jf : bj21;
                bd21 = fminf(d, bd21);
            }
            jf += 1.0f;
        }
    }

    // ---- Pack (d,idx) -> u32 (monotonic for d>=0; low 11 bits = idx;
    //      umin => min-d with lower idx on truncated tie) ----
    unsigned u10 = (__float_as_uint(bd10) & 0xFFFFF800u) | (unsigned)(int)bi10;
    unsigned u11 = (__float_as_uint(bd11) & 0xFFFFF800u) | (unsigned)(int)bi11;
    unsigned u20 = (__float_as_uint(bd20) & 0xFFFFF800u) | (unsigned)(int)bj20;
    unsigned u21 = (__float_as_uint(bd21) & 0xFFFFF800u) | (unsigned)(int)bj21;

    // Combine over groups: lane bits 3,4,5
    #pragma unroll
    for (int st = 8; st <= 32; st <<= 1) {
        u10 = min(u10, (unsigned)__shfl_xor((int)u10, st));
        u11 = min(u11, (unsigned)__shfl_xor((int)u11, st));
        u20 = min(u20, (unsigned)__shfl_xor((int)u20, st));
        u21 = min(u21, (unsigned)__shfl_xor((int)u21, st));
    }

    // ---- Epilogue on group-0 lanes (lane 0..7): 2 points + 2 vertices ----
    float l_a = 0.0f, l_c = 0.0f, l_m = 0.0f;
    if (grp == 0) {
        {
            const int idx = (int)(u10 & 0x7FFu);
            const int n = idx / 10;
            const int t = idx - n * 10;
            const float step = (float)t / 10.0f;     // exact ref: arange(T)/T
            const float om   = 1.0f - step;
            const float2 c   = s_gt[n];
            const float2 prv = s_gt[(n + NG - 1) & (NG - 1)];
            const float2 mp  = s_pp[pnt0];
            l_a += fabsf(mp.x - (c.x * step + prv.x * om))
                 + fabsf(mp.y - (c.y * step + prv.y * om));
        }
        {
            const int idx = (int)(u11 & 0x7FFu);
            const int n = idx / 10;
            const int t = idx - n * 10;
            const float step = (float)t / 10.0f;
            const float om   = 1.0f - step;
            const float2 c   = s_gt[n];
            const float2 prv = s_gt[(n + NG - 1) & (NG - 1)];
            const float2 mp  = s_pp[pnt1];
            l_a += fabsf(mp.x - (c.x * step + prv.x * om))
                 + fabsf(mp.y - (c.y * step + prv.y * om));
        }
        {
            const float2 npt = s_pp[(int)(u20 & 0x7FFu)];
            l_c += mv0 * (fabsf(npt.x - gv0.x) + fabsf(npt.y - gv0.y));
            l_m += 2.0f * mv0;
        }
        {
            const float2 npt = s_pp[(int)(u21 & 0x7FFu)];
            l_c += mv1 * (fabsf(npt.x - gv1.x) + fabsf(npt.y - gv1.y));
            l_m += 2.0f * mv1;
        }
    }

    // Sum-reduce the 8 group-0 lanes (bits 0..2; other lanes carry zeros)
    #pragma unroll
    for (int st = 1; st <= 4; st <<= 1) {
        l_a += __shfl_xor(l_a, st);
        l_c += __shfl_xor(l_c, st);
        l_m += __shfl_xor(l_m, st);
    }
    if (lane == 0) {
        s_red[w * 3 + 0] = l_a;
        s_red[w * 3 + 1] = l_c;
        s_red[w * 3 + 2] = l_m;
    }
    __syncthreads();
    if (tid < 3) {
        float s = 0.0f;
        #pragma unroll
        for (int ww = 0; ww < 8; ++ww) s += s_red[ww * 3 + tid];
        partial[(size_t)tid * nb + b] = s;           // SoA -> coalesced final
    }
}

__global__ __launch_bounds__(256) void dm_final(
    const float* __restrict__ partial, int nb, double inv_count, float* __restrict__ out)
{
    const int tid = threadIdx.x;
    double a = 0.0, c = 0.0, d = 0.0;
    if ((nb & 3) == 0) {
        const int npairs = nb >> 2;
        for (int i = tid; i < npairs; i += 256) {
            const float4 va = ((const float4*)partial)[i];
            const float4 vc = ((const float4*)(partial + (size_t)nb))[i];
            const float4 vd = ((const float4*)(partial + (size_t)2 * nb))[i];
            a += (double)va.x + (double)va.y + (double)va.z + (double)va.w;
            c += (double)vc.x + (double)vc.y + (double)vc.z + (double)vc.w;
            d += (double)vd.x + (double)vd.y + (double)vd.z + (double)vd.w;
        }
    } else {
        for (int i = tid; i < nb; i += 256) {
            a += (double)partial[i];
            c += (double)partial[(size_t)nb + i];
            d += (double)partial[(size_t)2 * nb + i];
        }
    }
    for (int off = 32; off > 0; off >>= 1) {
        a += __shfl_down(a, off);
        c += __shfl_down(c, off);
        d += __shfl_down(d, off);
    }
    __shared__ double s[12];
    const int wid = tid >> 6, lane = tid & 63;
    if (lane == 0) { s[wid * 3] = a; s[wid * 3 + 1] = c; s[wid * 3 + 2] = d; }
    __syncthreads();
    if (tid == 0) {
        const double at = s[0] + s[3] + s[6] + s[9];
        const double ct = s[1] + s[4] + s[7] + s[10];
        const double dt = s[2] + s[5] + s[8] + s[11];
        const double loss = ct / (dt + 1.0) + at * inv_count;
        out[0] = (float)(loss * 0.5);
    }
}

extern "C" void kernel_launch(void* const* d_in, const int* in_sizes, int n_in,
                              void* d_out, int out_size, void* d_ws, size_t ws_size,
                              hipStream_t stream) {
    const float* ini  = (const float*)d_in[0];
    const float* pp   = (const float*)d_in[1];
    const float* gt   = (const float*)d_in[2];
    const float* mask = (const float*)d_in[3];
    float* out = (float*)d_out;

    const int B = in_sizes[0] / (NP * 2);
    float* partial = (float*)d_ws;                   // 3*B floats

    dm_main<<<B, 512, 0, stream>>>(ini, pp, gt, mask, partial, B);
    const double inv_count = 1.0 / ((double)B * NP * 2);
    dm_final<<<1, 256, 0, stream>>>(partial, B, inv_count, out);
}

// Round 13
// 18.679 us; speedup vs baseline: 1.0216x; 1.0216x over previous
//
#include <hip/hip_runtime.h>

// DMLoss: B=1024, Np=Ng=128, T=10.
// Round 13: r10 anchor (17.25us) + ILP levers only. Model update: dm_main is
// LATENCY-bound (issue-count models say ~5us; halving LDS ops (r11/r12) did
// nothing; r1 was genuinely VALU-bound but r10 is ~4x leaner). Changes:
//  1. FUSED scan loop: 16 iters x {2 part-1 evals + 1 part-2 float4 pair}.
//     Independent streams fill each other's ds_read latency shadows.
//  2. Epilogue split: quarter-0 lanes do part-1 interp/L1, quarter-1 lanes do
//     part-2 gather/mask (mask prefetched on q1). Halves divergent span.
//     Sum-reduce = 6 butterfly steps (q2/q3 carry zeros).
//  Everything else verbatim r10: stride-33 pad s_seg/s_g, stride-17 pad
//  s_ini2, score-form part-1 (rcp once in staging — r6/r9 lesson), r10's
//  exact 2-step tie-break combine, SoA partials, two-kernel finish
//  (cross-block atomics cost ~40us: r3/r7).

constexpr int NP = 128;
constexpr int NG = 128;

__device__ __forceinline__ int padi (int i) { return i + (i >> 5); }  // stride-33
__device__ __forceinline__ int padi2(int i) { return i + (i >> 4); }  // stride-17

__global__ __launch_bounds__(512) void dm_main(
    const float* __restrict__ ini,   // [B, NP, 2]
    const float* __restrict__ pp,    // [B, NP, 2]
    const float* __restrict__ gt,    // [B, NG, 2]
    const float* __restrict__ mask,  // [B, NG]
    float* __restrict__ partial,     // SoA: [3][B]
    int nb)
{
    const int b    = blockIdx.x;
    const int tid  = threadIdx.x;
    const int lane = tid & 63;
    const int w    = tid >> 6;             // wave 0..7

    __shared__ float2 s_gt  [NG];          // epilogue gathers (unpadded)
    __shared__ float4 s_seg [NG + 4];      // padded(>>5): {pv.x, pv.y, e10x, e10y}
    __shared__ float  s_g   [NG + 4];      // padded(>>5): |e|^2 / 100
    __shared__ float4 s_ini2[64 + 4];      // padded(>>4): {p0.x,p0.y,p1.x,p1.y}
    __shared__ float2 s_pp  [NP];          // epilogue gathers (unpadded)
    __shared__ float  s_red [24];

    const float2* gtb  = (const float2*)(gt  + (size_t)b * 256);
    const float4* ini4 = (const float4*)(ini + (size_t)b * 256);
    const float2* ppb  = (const float2*)(pp  + (size_t)b * 256);

    // Staging; rcp ONCE per segment here (r6/r9 lesson: never in-loop).
    if (tid < 128) {
        const float2 cv = gtb[tid];
        const float2 pv = gtb[(tid + 127) & 127];
        const float ex = cv.x - pv.x, ey = cv.y - pv.y;
        const float ee = fmaf(ex, ex, ey * ey);
        const float s10 = 10.0f * __builtin_amdgcn_rcpf(fmaxf(ee, 1e-30f));
        s_gt [tid]       = cv;
        s_seg[padi(tid)] = make_float4(pv.x, pv.y, ex * s10, ey * s10);
        s_g  [padi(tid)] = ee * 0.01f;
    } else if (tid < 192) {
        const int i = tid - 128;           // pred pair 0..63
        s_ini2[padi2(i)] = ini4[i];
    } else if (tid < 320) {
        s_pp[tid - 192] = ppb[tid - 192];
    }

    const int sub     = lane & 15;         // point/vertex within wave's 16
    const int quarter = lane >> 4;         // 0..3
    const int pnt     = (w << 4) | sub;    // 0..127
    float mval = 0.0f;
    if (quarter == 1) mval = mask[(size_t)b * NG + pnt];   // q1 does part-2 epi
    __syncthreads();

    // Queries from the packed pair table (broadcast-ish one-time reads)
    const float4 qq = s_ini2[padi2(pnt >> 1)];
    const float2 q  = (pnt & 1) ? make_float2(qq.z, qq.w) : make_float2(qq.x, qq.y);
    const float2 gv = s_gt[pnt];

    // ---- FUSED scan: 16 iters x {2 part-1 segs + 1 part-2 pred pair} ----
    float bd1 = 3.4e38f, bi1 = 0.0f;
    float bd2 = 3.4e38f, bj2 = 0.0f;
    {
        const int s0 = quarter << 5;       // part-1 segment base
        const int p0 = quarter << 4;       // part-2 pair base
        float basef = (float)(s0 * 10);
        float jf    = (float)(quarter << 5);
        #pragma unroll 4
        for (int k = 0; k < 16; ++k) {
            // part-1 eval: segment s0+2k
            {
                const float4 sg = s_seg[padi(s0 + 2 * k)];
                const float  g  = s_g  [padi(s0 + 2 * k)];
                const float wx = q.x - sg.x, wy = q.y - sg.y;
                const float tf = fmaf(wy, sg.w, wx * sg.z);
                float tc = rintf(tf);
                tc = __builtin_amdgcn_fmed3f(tc, 0.0f, 9.0f);
                const float ww = fmaf(wy, wy, wx * wx);
                const float d  = fmaf(g * tc, fmaf(-2.0f, tf, tc), ww);
                const float cand = basef + tc;
                bi1 = (d < bd1) ? cand : bi1;         // strict <: first occurrence
                bd1 = fminf(d, bd1);
            }
            // part-1 eval: segment s0+2k+1
            {
                const float4 sg = s_seg[padi(s0 + 2 * k + 1)];
                const float  g  = s_g  [padi(s0 + 2 * k + 1)];
                const float wx = q.x - sg.x, wy = q.y - sg.y;
                const float tf = fmaf(wy, sg.w, wx * sg.z);
                float tc = rintf(tf);
                tc = __builtin_amdgcn_fmed3f(tc, 0.0f, 9.0f);
                const float ww = fmaf(wy, wy, wx * wx);
                const float d  = fmaf(g * tc, fmaf(-2.0f, tf, tc), ww);
                const float cand = basef + 10.0f + tc;
                bi1 = (d < bd1) ? cand : bi1;
                bd1 = fminf(d, bd1);
            }
            // part-2 evals: pred pair p0+k
            {
                const float4 pv2 = s_ini2[padi2(p0 + k)];
                {
                    const float dx = gv.x - pv2.x, dy = gv.y - pv2.y;
                    const float d  = fmaf(dy, dy, dx * dx);
                    bj2 = (d < bd2) ? jf : bj2;
                    bd2 = fminf(d, bd2);
                }
                {
                    const float dx = gv.x - pv2.z, dy = gv.y - pv2.w;
                    const float d  = fmaf(dy, dy, dx * dx);
                    bj2 = (d < bd2) ? (jf + 1.0f) : bj2;
                    bd2 = fminf(d, bd2);
                }
            }
            basef += 20.0f;
            jf    += 2.0f;
        }
    }

    // ---- In-wave combine over quarters (lane bits 4,5); tie -> lower index.
    #pragma unroll
    for (int st = 16; st <= 32; st <<= 1) {
        const float d1o = __shfl_xor(bd1, st);
        const float i1o = __shfl_xor(bi1, st);
        const bool  t1  = (d1o < bd1) || (d1o == bd1 && i1o < bi1);
        bi1 = t1 ? i1o : bi1;
        bd1 = t1 ? d1o : bd1;
        const float d2o = __shfl_xor(bd2, st);
        const float j2o = __shfl_xor(bj2, st);
        const bool  t2  = (d2o < bd2) || (d2o == bd2 && j2o < bj2);
        bj2 = t2 ? j2o : bj2;
        bd2 = t2 ? d2o : bd2;
    }

    // ---- Split epilogue: q0 lanes -> part 1; q1 lanes -> part 2 ----
    float l_a = 0.0f, l_c = 0.0f, l_m = 0.0f;
    if (quarter == 0) {
        const int idx = (int)bi1;
        const int n = idx / 10;                       // magic-mul
        const int t = idx - n * 10;
        const float step = (float)t / 10.0f;          // exact ref: arange(T)/T
        const float om   = 1.0f - step;
        const float2 c   = s_gt[n];
        const float2 prv = s_gt[(n + NG - 1) & (NG - 1)];
        const float nx = c.x * step + prv.x * om;
        const float ny = c.y * step + prv.y * om;
        const float2 mp = s_pp[pnt];
        l_a = fabsf(mp.x - nx) + fabsf(mp.y - ny);
    } else if (quarter == 1) {
        const float2 npt = s_pp[(int)bj2];
        l_c = mval * (fabsf(npt.x - gv.x) + fabsf(npt.y - gv.y));
        l_m = 2.0f * mval;
    }

    // Sum-reduce: bits 0..3 within quarter, then bits 4,5 across quarters
    // (q2/q3 carry zeros).
    #pragma unroll
    for (int st = 1; st <= 32; st <<= 1) {
        l_a += __shfl_xor(l_a, st);
        l_c += __shfl_xor(l_c, st);
        l_m += __shfl_xor(l_m, st);
    }
    if (lane == 0) {
        s_red[w * 3 + 0] = l_a;
        s_red[w * 3 + 1] = l_c;
        s_red[w * 3 + 2] = l_m;
    }
    __syncthreads();
    if (tid < 3) {
        float s = 0.0f;
        #pragma unroll
        for (int ww = 0; ww < 8; ++ww) s += s_red[ww * 3 + tid];
        partial[(size_t)tid * nb + b] = s;            // SoA -> coalesced final
    }
}

__global__ __launch_bounds__(256) void dm_final(
    const float* __restrict__ partial, int nb, double inv_count, float* __restrict__ out)
{
    const int tid = threadIdx.x;
    double a = 0.0, c = 0.0, d = 0.0;
    if ((nb & 3) == 0) {
        const int npairs = nb >> 2;                   // float4s per stream
        for (int i = tid; i < npairs; i += 256) {
            const float4 va = ((const float4*)partial)[i];
            const float4 vc = ((const float4*)(partial + (size_t)nb))[i];
            const float4 vd = ((const float4*)(partial + (size_t)2 * nb))[i];
            a += (double)va.x + (double)va.y + (double)va.z + (double)va.w;
            c += (double)vc.x + (double)vc.y + (double)vc.z + (double)vc.w;
            d += (double)vd.x + (double)vd.y + (double)vd.z + (double)vd.w;
        }
    } else {
        for (int i = tid; i < nb; i += 256) {
            a += (double)partial[i];
            c += (double)partial[(size_t)nb + i];
            d += (double)partial[(size_t)2 * nb + i];
        }
    }
    for (int off = 32; off > 0; off >>= 1) {
        a += __shfl_down(a, off);
        c += __shfl_down(c, off);
        d += __shfl_down(d, off);
    }
    __shared__ double s[12];
    const int wid = tid >> 6, lane = tid & 63;
    if (lane == 0) { s[wid * 3] = a; s[wid * 3 + 1] = c; s[wid * 3 + 2] = d; }
    __syncthreads();
    if (tid == 0) {
        const double at = s[0] + s[3] + s[6] + s[9];
        const double ct = s[1] + s[4] + s[7] + s[10];
        const double dt = s[2] + s[5] + s[8] + s[11];
        const double loss = ct / (dt + 1.0) + at * inv_count;
        out[0] = (float)(loss * 0.5);
    }
}

extern "C" void kernel_launch(void* const* d_in, const int* in_sizes, int n_in,
                              void* d_out, int out_size, void* d_ws, size_t ws_size,
                              hipStream_t stream) {
    const float* ini  = (const float*)d_in[0];
    const float* pp   = (const float*)d_in[1];
    const float* gt   = (const float*)d_in[2];
    const float* mask = (const float*)d_in[3];
    float* out = (float*)d_out;

    const int B = in_sizes[0] / (NP * 2);
    float* partial = (float*)d_ws;                    // 3*B floats

    dm_main<<<B, 512, 0, stream>>>(ini, pp, gt, mask, partial, B);
    const double inv_count = 1.0 / ((double)B * NP * 2);
    dm_final<<<1, 256, 0, stream>>>(partial, B, inv_count, out);
}